// Round 5
// baseline (468.005 us; speedup 1.0000x reference)
//
#include <hip/hip_runtime.h>

// PointPillarScatter: out[b, c, y, x] = feat[p, c] where pillar p sits at (b, y, x), else 0.
// NX=432, NY=496, NZ=1, C=64, B=8 (B derived from out_size).
// Inverse-map approach: cell -> pillar map in d_ws, then one fully-coalesced gather pass
// writing every output element exactly once (zero or feature).
// R5: all 16 feat gathers issued up-front per thread (max MLP, hides ~200-900 cyc
//     gather latency), full register transpose, 16 nontemporal 1KB/wave stores.
//     Model: ~360 us of dur_us is harness-fixed (d_ws+d_out poison fills + d_in
//     restore); our kernels ~100-110 us vs ~85 us traffic floor.

#define NXC   432
#define NYC   496
#define CCH   64
#define PLANE (NXC * NYC)        // 214272 cells per (batch, channel) plane
#define CB    256                // cells per gather block; 214272 = 837 * 256

typedef float vfloat4 __attribute__((ext_vector_type(4)));
typedef int   vint4   __attribute__((ext_vector_type(4)));

__global__ __launch_bounds__(256) void init_map_kernel(int* __restrict__ map, int n4) {
    int i = blockIdx.x * blockDim.x + threadIdx.x;
    if (i < n4) {
        vint4 m = { -1, -1, -1, -1 };
        __builtin_nontemporal_store(m, (vint4*)map + i);
    }
}

__global__ __launch_bounds__(256) void scatter_idx_kernel(const int* __restrict__ coords,
                                                          int* __restrict__ map, int P) {
    int p = blockIdx.x * blockDim.x + threadIdx.x;
    if (p < P) {
        int4 c = ((const int4*)coords)[p];   // [b, z, y, x]
        int flat = c.x * PLANE + (c.y + c.z * NXC + c.w);  // z term is 0 (NZ=1)
        map[flat] = p;
    }
}

// Block = 256 cells x 64 channels. Wave w (0..3) owns channels [16w, 16w+16),
// lane l (0..63) owns cells [4l, 4l+4). All 16 16B feat gathers issued before any
// use; 4x16 register transpose; 16 nontemporal float4 stores (1 KB/wave-instr).
__global__ __launch_bounds__(256) void gather_kernel(const float* __restrict__ feat,
                                                     const int* __restrict__ map,
                                                     float* __restrict__ out, int P) {
    const int tid   = threadIdx.x;
    const int w     = tid >> 6;                      // wave -> channel group base 16w
    const int l     = tid & 63;                      // lane -> cell group
    const int bpb   = PLANE / CB;                    // 837 blocks per batch
    const int cb    = blockIdx.x % bpb;
    const int b     = blockIdx.x / bpb;
    const int cell0 = cb * CB;

    // coalesced map read: 64 lanes x int4 = 1 KB (waves share lines via L1)
    const int4 pm = ((const int4*)(map + (long)b * PLANE + cell0))[l];
    const int pidx[4] = { pm.x, pm.y, pm.z, pm.w };
    const unsigned uP = (unsigned)P;

    const float* fbase = feat + (long)(w * 16);
    float*       obase = out + (long)(b * CCH + w * 16) * PLANE + cell0 + 4 * l;

    // Issue all 16 independent gathers (4 cells x 4 channel-quads) before any use.
    vfloat4 v[4][4];                                 // [cell][chan-quad]
    #pragma unroll
    for (int i = 0; i < 4; ++i) {
        const bool ok = (unsigned)pidx[i] < uP;
        const vfloat4* src = (const vfloat4*)(fbase + (long)pidx[i] * CCH);
        #pragma unroll
        for (int k = 0; k < 4; ++k) {
            v[i][k] = ok ? src[k] : (vfloat4)(0.f);
        }
    }

    // Transpose: channel c = 4k+j -> float4 across the 4 consecutive cells.
    #pragma unroll
    for (int k = 0; k < 4; ++k) {
        float* o = obase + (long)(k * 4) * PLANE;
        vfloat4 t0 = { v[0][k].x, v[1][k].x, v[2][k].x, v[3][k].x };
        vfloat4 t1 = { v[0][k].y, v[1][k].y, v[2][k].y, v[3][k].y };
        vfloat4 t2 = { v[0][k].z, v[1][k].z, v[2][k].z, v[3][k].z };
        vfloat4 t3 = { v[0][k].w, v[1][k].w, v[2][k].w, v[3][k].w };
        __builtin_nontemporal_store(t0, (vfloat4*)(o));
        __builtin_nontemporal_store(t1, (vfloat4*)(o + 1L * PLANE));
        __builtin_nontemporal_store(t2, (vfloat4*)(o + 2L * PLANE));
        __builtin_nontemporal_store(t3, (vfloat4*)(o + 3L * PLANE));
    }
}

extern "C" void kernel_launch(void* const* d_in, const int* in_sizes, int n_in,
                              void* d_out, int out_size, void* d_ws, size_t ws_size,
                              hipStream_t stream) {
    const float* x0     = (const float*)d_in[0];
    const int*   coords = (const int*)d_in[1];
    float*       out    = (float*)d_out;

    const int P = in_sizes[0] / CCH;                 // 128000 pillars
    const int B = out_size / (CCH * PLANE);          // 8

    int* map = (int*)d_ws;                           // B*PLANE int32 = 6.86 MB scratch

    // 1) init map to -1 (any value with (unsigned)v >= P marks empty)
    const int n4 = (B * PLANE) / 4;
    init_map_kernel<<<(n4 + 255) / 256, 256, 0, stream>>>(map, n4);

    // 2) scatter pillar index into map
    scatter_idx_kernel<<<(P + 255) / 256, 256, 0, stream>>>(coords, map, P);

    // 3) gather pass: write full output, fully coalesced, float4-wide, nontemporal
    const int nblocks = B * (PLANE / CB);            // 6696
    gather_kernel<<<nblocks, 256, 0, stream>>>(x0, map, out, P);
}